// Round 7
// baseline (311.940 us; speedup 1.0000x reference)
//
#include <hip/hip_runtime.h>
#include <hip/hip_bf16.h>
#include <cstdint>

#define KDIM 1024
#define BDIM 8192
#define VDIM 2
#define NBLK 16  // KDIM / 64

typedef __attribute__((ext_vector_type(8))) short short8;
typedef __attribute__((ext_vector_type(4))) float f32x4;

__device__ inline unsigned short f2bf(float x) {
  unsigned u = __builtin_bit_cast(unsigned, x);
  u = (u + 0x7FFFu + ((u >> 16) & 1u)) >> 16;
  return (unsigned short)u;
}

// ---------------------------------------------------------------------------
// inv_base: one WG per 256-wide diagonal super-block (4 WGs total).
//   Phase A: invert the 4 diagonal 64x64 unit-lower blocks (thread/column),
//            float4-batched LDS row loads (latency batched per row, not per
//            element — the round-6 version was LDS-latency-serialized).
//   Phase B: two h=64 combines   (M21 = M22*A21*M11), P held in LDS.
//   Phase C: one h=128 combine, P held in LDS, triangular chunk skip.
// MT[j][i] = M[i][j]. Only the upper (i>=j) block-triangle of MT is written.
// ---------------------------------------------------------------------------
__global__ __launch_bounds__(256) void inv_base(const float* __restrict__ A,
                                                float* __restrict__ MT) {
  __shared__ float Ps[128][132];  // 67.6 KB; doubles as As (16384 fl) in phase A
  __shared__ float Ls[64][68];
  __shared__ float Rs[64][68];

  const int sbase = blockIdx.x * 256;
  const int tid = threadIdx.x;
  const int k4 = tid & 15, rw = tid >> 4;
  const int tm = tid >> 4, tn = tid & 15;

  // ---------------- Phase A: 4 diagonal 64x64 inversions ----------------
  {
    float* As = (float*)Ps;  // 4 blocks * 4096 floats
    const int g = tid >> 6, lane = tid & 63;
    const int bb = sbase + g * 64;
    for (int r = 0; r < 64; ++r)
      As[g * 4096 + r * 64 + lane] = A[(size_t)(bb + r) * KDIM + bb + lane];
    __syncthreads();

    const int c = lane;
    float m[64];
#pragma unroll
    for (int r = 0; r < 64; ++r) m[r] = (r == c) ? 1.f : 0.f;

    // forward substitution. For threads where the result matters (r > c),
    // m[i] == 0 for all i >= r (only nonzero init is at i = c < r), so a
    // full-prefix dot needs no masking. Threads with c >= r discard v.
#pragma unroll
    for (int r = 1; r < 64; ++r) {
      const float* Arow = As + g * 4096 + r * 64;
      const int nch = (r >> 2) + 1;  // chunks covering i < r (extra lanes hit 0)
      float4 rv[16];
#pragma unroll
      for (int ii = 0; ii < 16; ++ii) {
        if (ii >= nch) break;
        rv[ii] = *(const float4*)(Arow + 4 * ii);
      }
      float a0 = 0.f, a1 = 0.f, a2 = 0.f, a3 = 0.f;
#pragma unroll
      for (int ii = 0; ii < 16; ++ii) {
        if (ii >= nch) break;
        a0 += rv[ii].x * m[4 * ii + 0];
        a1 += rv[ii].y * m[4 * ii + 1];
        a2 += rv[ii].z * m[4 * ii + 2];
        a3 += rv[ii].w * m[4 * ii + 3];
      }
      const float v = (a0 + a1) + (a2 + a3);
      m[r] = (r > c) ? v : m[r];
    }
    // MT[bb+c][bb+r] = T_g[r][c]
#pragma unroll
    for (int r = 0; r < 64; r += 4) {
      float4 v = make_float4(m[r], m[r + 1], m[r + 2], m[r + 3]);
      *(float4*)(MT + (size_t)(bb + c) * KDIM + bb + r) = v;
    }
  }
  __threadfence();
  __syncthreads();

  // ---------------- Phase B: two h=64 combines ----------------
  for (int cmb = 0; cmb < 2; ++cmb) {
    const int cb = sbase + 128 * cmb;
    __syncthreads();
    // P: Pt[j][r] = sum_c MT11[j][c] * A21[r][c]
#pragma unroll
    for (int p = 0; p < 4; ++p) {
      const int m = p * 16 + rw;
      float4 lv = *(const float4*)(MT + (size_t)(cb + m) * KDIM + cb + 4 * k4);
      Ls[4 * k4 + 0][m] = lv.x;
      Ls[4 * k4 + 1][m] = lv.y;
      Ls[4 * k4 + 2][m] = lv.z;
      Ls[4 * k4 + 3][m] = lv.w;
      float4 rv =
          *(const float4*)(A + (size_t)(cb + 64 + m) * KDIM + cb + 4 * k4);
      Rs[4 * k4 + 0][m] = rv.x;
      Rs[4 * k4 + 1][m] = rv.y;
      Rs[4 * k4 + 2][m] = rv.z;
      Rs[4 * k4 + 3][m] = rv.w;
    }
    __syncthreads();
    float acc[4][4];
#pragma unroll
    for (int a = 0; a < 4; ++a)
#pragma unroll
      for (int b = 0; b < 4; ++b) acc[a][b] = 0.f;
#pragma unroll 4
    for (int k = 0; k < 64; ++k) {
      float4 av = *(const float4*)&Ls[k][4 * tm];
      float4 bv = *(const float4*)&Rs[k][4 * tn];
      const float aa[4] = {av.x, av.y, av.z, av.w};
      const float bb4[4] = {bv.x, bv.y, bv.z, bv.w};
#pragma unroll
      for (int a = 0; a < 4; ++a)
#pragma unroll
        for (int b = 0; b < 4; ++b) acc[a][b] += aa[a] * bb4[b];
    }
    // store P transposed: Ps[r][j] = Pt[j][r]
#pragma unroll
    for (int a = 0; a < 4; ++a)
#pragma unroll
      for (int b = 0; b < 4; ++b) Ps[4 * tn + b][4 * tm + a] = acc[a][b];
    __syncthreads();
    // Q: out[j][r] = sum_c Pt[j][c] * MT22[c][r]
#pragma unroll
    for (int p = 0; p < 4; ++p) {
      const int kk = p * 16 + rw;
      *(float4*)&Rs[kk][4 * k4] =
          *(const float4*)(MT + (size_t)(cb + 64 + kk) * KDIM + cb + 64 + 4 * k4);
    }
    __syncthreads();
#pragma unroll
    for (int a = 0; a < 4; ++a)
#pragma unroll
      for (int b = 0; b < 4; ++b) acc[a][b] = 0.f;
#pragma unroll 4
    for (int k = 0; k < 64; ++k) {
      float4 av = *(const float4*)&Ps[k][4 * tm];
      float4 bv = *(const float4*)&Rs[k][4 * tn];
      const float aa[4] = {av.x, av.y, av.z, av.w};
      const float bb4[4] = {bv.x, bv.y, bv.z, bv.w};
#pragma unroll
      for (int a = 0; a < 4; ++a)
#pragma unroll
        for (int b = 0; b < 4; ++b) acc[a][b] += aa[a] * bb4[b];
    }
#pragma unroll
    for (int a = 0; a < 4; ++a) {
      float4 o = make_float4(acc[a][0], acc[a][1], acc[a][2], acc[a][3]);
      *(float4*)(MT + (size_t)(cb + 4 * tm + a) * KDIM + cb + 64 + 4 * tn) = o;
    }
  }
  __threadfence();
  __syncthreads();

  // ---------------- Phase C: h=128 combine ----------------
  // P2[j][r] = sum_c MT11[j][c]*A21[r][c], j,r in [0,128); skip kc<jt (zero)
  for (int tile = 0; tile < 4; ++tile) {
    const int jt = tile >> 1, rt = tile & 1;
    float acc[4][4];
#pragma unroll
    for (int a = 0; a < 4; ++a)
#pragma unroll
      for (int b = 0; b < 4; ++b) acc[a][b] = 0.f;
    for (int kc = jt; kc < 2; ++kc) {
      __syncthreads();
#pragma unroll
      for (int p = 0; p < 4; ++p) {
        const int m = p * 16 + rw;
        float4 lv = *(const float4*)(MT + (size_t)(sbase + jt * 64 + m) * KDIM +
                                     sbase + kc * 64 + 4 * k4);
        Ls[4 * k4 + 0][m] = lv.x;
        Ls[4 * k4 + 1][m] = lv.y;
        Ls[4 * k4 + 2][m] = lv.z;
        Ls[4 * k4 + 3][m] = lv.w;
        float4 rv =
            *(const float4*)(A + (size_t)(sbase + 128 + rt * 64 + m) * KDIM +
                             sbase + kc * 64 + 4 * k4);
        Rs[4 * k4 + 0][m] = rv.x;
        Rs[4 * k4 + 1][m] = rv.y;
        Rs[4 * k4 + 2][m] = rv.z;
        Rs[4 * k4 + 3][m] = rv.w;
      }
      __syncthreads();
#pragma unroll 4
      for (int k = 0; k < 64; ++k) {
        float4 av = *(const float4*)&Ls[k][4 * tm];
        float4 bv = *(const float4*)&Rs[k][4 * tn];
        const float aa[4] = {av.x, av.y, av.z, av.w};
        const float bb4[4] = {bv.x, bv.y, bv.z, bv.w};
#pragma unroll
        for (int a = 0; a < 4; ++a)
#pragma unroll
          for (int b = 0; b < 4; ++b) acc[a][b] += aa[a] * bb4[b];
      }
    }
    __syncthreads();
#pragma unroll
    for (int a = 0; a < 4; ++a)
#pragma unroll
      for (int b = 0; b < 4; ++b)
        Ps[rt * 64 + 4 * tn + b][jt * 64 + 4 * tm + a] = acc[a][b];
  }
  // Q2: out[j][r] = sum_c P2[j][c]*MT22[c][r]; skip kc>rt (zero)
  for (int tile = 0; tile < 4; ++tile) {
    const int jt = tile >> 1, rt = tile & 1;
    float acc[4][4];
#pragma unroll
    for (int a = 0; a < 4; ++a)
#pragma unroll
      for (int b = 0; b < 4; ++b) acc[a][b] = 0.f;
    for (int kc = 0; kc <= rt; ++kc) {
      __syncthreads();
#pragma unroll
      for (int p = 0; p < 4; ++p) {
        const int kk = p * 16 + rw;
        *(float4*)&Rs[kk][4 * k4] =
            *(const float4*)(MT + (size_t)(sbase + 128 + kc * 64 + kk) * KDIM +
                             sbase + 128 + rt * 64 + 4 * k4);
      }
      __syncthreads();
#pragma unroll 4
      for (int k = 0; k < 64; ++k) {
        float4 av = *(const float4*)&Ps[kc * 64 + k][jt * 64 + 4 * tm];
        float4 bv = *(const float4*)&Rs[k][4 * tn];
        const float aa[4] = {av.x, av.y, av.z, av.w};
        const float bb4[4] = {bv.x, bv.y, bv.z, bv.w};
#pragma unroll
        for (int a = 0; a < 4; ++a)
#pragma unroll
          for (int b = 0; b < 4; ++b) acc[a][b] += aa[a] * bb4[b];
      }
    }
#pragma unroll
    for (int a = 0; a < 4; ++a) {
      float4 o = make_float4(acc[a][0], acc[a][1], acc[a][2], acc[a][3]);
      *(float4*)(MT + (size_t)(sbase + jt * 64 + 4 * tm + a) * KDIM + sbase +
                 128 + rt * 64 + 4 * tn) = o;
    }
  }
}

// ---------------------------------------------------------------------------
// comb_p2: Pt[j][r] = sum_c MT11[j][c] * A21[r][c]   (full-K per tile,
// triangular skip kc>=jt, plain stores — no atomics, no pre-zero).
// grid = combines * t * t,  t = h/64.
// ---------------------------------------------------------------------------
__global__ __launch_bounds__(256) void comb_p2(const float* __restrict__ A,
                                               const float* __restrict__ MT,
                                               float* __restrict__ Pt, int h) {
  const int t = h >> 6;
  int b = blockIdx.x;
  const int rt = b % t; b /= t;
  const int jt = b % t; b /= t;
  const int c = b;
  const int base = c * 2 * h;

  __shared__ float Ls[64][68];
  __shared__ float Rs[64][68];
  const int tid = threadIdx.x;
  const int k4 = tid & 15, rw = tid >> 4;
  const int tm = tid >> 4, tn = tid & 15;

  float acc[4][4];
#pragma unroll
  for (int a = 0; a < 4; ++a)
#pragma unroll
    for (int bb = 0; bb < 4; ++bb) acc[a][bb] = 0.f;

  for (int kc = jt; kc < t; ++kc) {
    __syncthreads();
#pragma unroll
    for (int p = 0; p < 4; ++p) {
      const int m = p * 16 + rw;
      float4 lv = *(const float4*)(MT + (size_t)(base + jt * 64 + m) * KDIM +
                                   base + kc * 64 + 4 * k4);
      Ls[4 * k4 + 0][m] = lv.x;
      Ls[4 * k4 + 1][m] = lv.y;
      Ls[4 * k4 + 2][m] = lv.z;
      Ls[4 * k4 + 3][m] = lv.w;
      float4 rv = *(const float4*)(A + (size_t)(base + h + rt * 64 + m) * KDIM +
                                   base + kc * 64 + 4 * k4);
      Rs[4 * k4 + 0][m] = rv.x;
      Rs[4 * k4 + 1][m] = rv.y;
      Rs[4 * k4 + 2][m] = rv.z;
      Rs[4 * k4 + 3][m] = rv.w;
    }
    __syncthreads();
#pragma unroll 4
    for (int k = 0; k < 64; ++k) {
      float4 av = *(const float4*)&Ls[k][4 * tm];
      float4 bv = *(const float4*)&Rs[k][4 * tn];
      const float aa[4] = {av.x, av.y, av.z, av.w};
      const float bb4[4] = {bv.x, bv.y, bv.z, bv.w};
#pragma unroll
      for (int a = 0; a < 4; ++a)
#pragma unroll
        for (int bb = 0; bb < 4; ++bb) acc[a][bb] += aa[a] * bb4[bb];
    }
  }
#pragma unroll
  for (int a = 0; a < 4; ++a) {
    float4 o = make_float4(acc[a][0], acc[a][1], acc[a][2], acc[a][3]);
    *(float4*)(Pt + (size_t)c * h * h + (size_t)(jt * 64 + 4 * tm + a) * h +
               rt * 64 + 4 * tn) = o;
  }
}

// ---------------------------------------------------------------------------
// comb_q2: MT21t[j][r] = sum_c Pt[j][c] * MT22[c][r]   (skip kc>rt).
// ---------------------------------------------------------------------------
__global__ __launch_bounds__(256) void comb_q2(float* __restrict__ MT,
                                               const float* __restrict__ Pt,
                                               int h) {
  const int t = h >> 6;
  int b = blockIdx.x;
  const int rt = b % t; b /= t;
  const int jt = b % t; b /= t;
  const int c = b;
  const int base = c * 2 * h;
  const float* P0 = Pt + (size_t)c * h * h;

  __shared__ float Ls[64][68];
  __shared__ float Rs[64][68];
  const int tid = threadIdx.x;
  const int k4 = tid & 15, rw = tid >> 4;
  const int tm = tid >> 4, tn = tid & 15;

  float acc[4][4];
#pragma unroll
  for (int a = 0; a < 4; ++a)
#pragma unroll
    for (int bb = 0; bb < 4; ++bb) acc[a][bb] = 0.f;

  for (int kc = 0; kc <= rt; ++kc) {
    __syncthreads();
#pragma unroll
    for (int p = 0; p < 4; ++p) {
      const int m = p * 16 + rw;
      float4 lv = *(const float4*)(P0 + (size_t)(jt * 64 + m) * h + kc * 64 + 4 * k4);
      Ls[4 * k4 + 0][m] = lv.x;
      Ls[4 * k4 + 1][m] = lv.y;
      Ls[4 * k4 + 2][m] = lv.z;
      Ls[4 * k4 + 3][m] = lv.w;
      const int kk = p * 16 + rw;
      *(float4*)&Rs[kk][4 * k4] =
          *(const float4*)(MT + (size_t)(base + h + kc * 64 + kk) * KDIM +
                           base + h + rt * 64 + 4 * k4);
    }
    __syncthreads();
#pragma unroll 4
    for (int k = 0; k < 64; ++k) {
      float4 av = *(const float4*)&Ls[k][4 * tm];
      float4 bv = *(const float4*)&Rs[k][4 * tn];
      const float aa[4] = {av.x, av.y, av.z, av.w};
      const float bb4[4] = {bv.x, bv.y, bv.z, bv.w};
#pragma unroll
      for (int a = 0; a < 4; ++a)
#pragma unroll
        for (int bb = 0; bb < 4; ++bb) acc[a][bb] += aa[a] * bb4[bb];
    }
  }
#pragma unroll
  for (int a = 0; a < 4; ++a) {
    float4 o = make_float4(acc[a][0], acc[a][1], acc[a][2], acc[a][3]);
    *(float4*)(MT + (size_t)(base + jt * 64 + 4 * tm + a) * KDIM + base + h +
               rt * 64 + 4 * tn) = o;
  }
}

// ---------------------------------------------------------------------------
// mt2bf: Mbf[i][k] = bf16(MT[k][i]); tiles with ib<jb are structurally zero
// (MT there is unwritten garbage) — write zeros without reading.
// ---------------------------------------------------------------------------
__global__ __launch_bounds__(256) void mt2bf(const float* __restrict__ MT,
                                             unsigned short* __restrict__ Mbf) {
  const int ib = blockIdx.x & 15;
  const int jb = blockIdx.x >> 4;
  const int i0 = ib * 64, j0 = jb * 64;
  const int tr = threadIdx.x >> 4;
  const int tc = threadIdx.x & 15;

  if (ib < jb) {
    const ushort4 z = {0, 0, 0, 0};
#pragma unroll
    for (int p = 0; p < 4; ++p)
      *(ushort4*)(Mbf + (size_t)(i0 + p * 16 + tr) * KDIM + j0 + 4 * tc) = z;
    return;
  }

  __shared__ float tile[64][65];
#pragma unroll
  for (int p = 0; p < 4; ++p) {
    const int rj = p * 16 + tr;
    float4 v = *(const float4*)(MT + (size_t)(j0 + rj) * KDIM + i0 + 4 * tc);
    tile[rj][4 * tc + 0] = v.x;
    tile[rj][4 * tc + 1] = v.y;
    tile[rj][4 * tc + 2] = v.z;
    tile[rj][4 * tc + 3] = v.w;
  }
  __syncthreads();
#pragma unroll
  for (int p = 0; p < 4; ++p) {
    const int il = p * 16 + tr;
    ushort4 o;
    o.x = f2bf(tile[4 * tc + 0][il]);
    o.y = f2bf(tile[4 * tc + 1][il]);
    o.z = f2bf(tile[4 * tc + 2][il]);
    o.w = f2bf(tile[4 * tc + 3][il]);
    *(ushort4*)(Mbf + (size_t)(i0 + il) * KDIM + j0 + 4 * tc) = o;
  }
}

// ---------------------------------------------------------------------------
// bf16 MFMA GEMM, double-buffered K-loop (one barrier per k-block).
// C[b][i] = sum_k Z[b][k] * Mbf[i][k]   (NT), 128x128 tile, 4 waves.
// ---------------------------------------------------------------------------
#define LDB 72

__global__ __launch_bounds__(256) void gemm_mfma(
    const float* __restrict__ Z, const unsigned short* __restrict__ Mbf,
    float* __restrict__ C) {
  __shared__ unsigned short As[2][128][LDB];
  __shared__ unsigned short Bs[2][128][LDB];

  const int wg = blockIdx.x;
  const int t7 = wg & 7;
  const int ni = (t7 & 1) ? (7 - (t7 >> 1)) : (t7 >> 1);
  const int xb = wg >> 3;
  const int b0 = xb * 128;
  const int i0 = ni * 128;

  const int tid = threadIdx.x;
  const int w = tid >> 6;
  const int lane = tid & 63;
  const int wr = w >> 1, wc = w & 1;
  const int mlane = lane & 15;
  const int q = lane >> 4;

  const int rq = tid >> 4, kq = tid & 15;
  const int cb = tid >> 3, ck = tid & 7;

  f32x4 acc[4][4];
#pragma unroll
  for (int a = 0; a < 4; ++a)
#pragma unroll
    for (int b = 0; b < 4; ++b) acc[a][b] = (f32x4){0.f, 0.f, 0.f, 0.f};

  const int nkb = 2 * (ni + 1);

  float4 zr[8];
  uint4 br[4];

#pragma unroll
  for (int p = 0; p < 8; ++p)
    zr[p] = *(const float4*)(Z + (size_t)(b0 + p * 16 + rq) * KDIM + 4 * kq);
#pragma unroll
  for (int p = 0; p < 4; ++p)
    br[p] = *(const uint4*)(Mbf + (size_t)(i0 + p * 32 + cb) * KDIM + 8 * ck);
#pragma unroll
  for (int p = 0; p < 8; ++p) {
    ushort4 o;
    o.x = f2bf(zr[p].x);
    o.y = f2bf(zr[p].y);
    o.z = f2bf(zr[p].z);
    o.w = f2bf(zr[p].w);
    *(ushort4*)&As[0][p * 16 + rq][4 * kq] = o;
  }
#pragma unroll
  for (int p = 0; p < 4; ++p) *(uint4*)&Bs[0][p * 32 + cb][8 * ck] = br[p];
  __syncthreads();

  for (int kb = 0; kb < nkb; ++kb) {
    const int cur = kb & 1;
    const bool more = (kb + 1 < nkb);
    if (more) {
      const int k0 = (kb + 1) * 64;
#pragma unroll
      for (int p = 0; p < 8; ++p)
        zr[p] = *(const float4*)(Z + (size_t)(b0 + p * 16 + rq) * KDIM + k0 +
                                 4 * kq);
#pragma unroll
      for (int p = 0; p < 4; ++p)
        br[p] = *(const uint4*)(Mbf + (size_t)(i0 + p * 32 + cb) * KDIM + k0 +
                                8 * ck);
    }
#pragma unroll
    for (int ks = 0; ks < 2; ++ks) {
      const int kf = ks * 32 + q * 8;
      short8 av[4], bv[4];
#pragma unroll
      for (int a = 0; a < 4; ++a)
        av[a] = *(const short8*)&As[cur][wr * 64 + 16 * a + mlane][kf];
#pragma unroll
      for (int b = 0; b < 4; ++b)
        bv[b] = *(const short8*)&Bs[cur][wc * 64 + 16 * b + mlane][kf];
#pragma unroll
      for (int a = 0; a < 4; ++a)
#pragma unroll
        for (int b = 0; b < 4; ++b)
          acc[a][b] = __builtin_amdgcn_mfma_f32_16x16x32_bf16(av[a], bv[b],
                                                              acc[a][b], 0, 0, 0);
    }
    if (more) {
#pragma unroll
      for (int p = 0; p < 8; ++p) {
        ushort4 o;
        o.x = f2bf(zr[p].x);
        o.y = f2bf(zr[p].y);
        o.z = f2bf(zr[p].z);
        o.w = f2bf(zr[p].w);
        *(ushort4*)&As[cur ^ 1][p * 16 + rq][4 * kq] = o;
      }
#pragma unroll
      for (int p = 0; p < 4; ++p)
        *(uint4*)&Bs[cur ^ 1][p * 32 + cb][8 * ck] = br[p];
    }
    __syncthreads();
  }

#pragma unroll
  for (int a = 0; a < 4; ++a) {
    const int row0 = b0 + wr * 64 + 16 * a + q * 4;
#pragma unroll
    for (int b = 0; b < 4; ++b) {
      const int col = i0 + wc * 64 + 16 * b + mlane;
      float* Cp = C + (size_t)row0 * KDIM + col;
      Cp[0 * KDIM] = acc[a][b][0];
      Cp[1 * KDIM] = acc[a][b][1];
      Cp[2 * KDIM] = acc[a][b][2];
      Cp[3 * KDIM] = acc[a][b][3];
    }
  }
}

// ---------------------------------------------------------------------------
// correction_k: u[b,:] = g[b,:] + (v - g[b,t]) * MT[t,:], masked to i >= t
// (MT[t][i] for i below t's diagonal block is unwritten garbage; true M
// column t is zero there anyway).
// ---------------------------------------------------------------------------
__global__ __launch_bounds__(256) void correction_k(
    const float* __restrict__ z, const int* __restrict__ tgt,
    const int* __restrict__ var, const float* __restrict__ means,
    const float* __restrict__ lsc, const float* __restrict__ MT,
    float* __restrict__ out) {
  const int b = blockIdx.x;
  const int t = tgt[b];
  if (t < 0) return;
  const int v = var[b];
  const float mval = means[t * VDIM + v];
  const float sval = expf(lsc[t * VDIM + v]);
  const float zv = z[(size_t)b * KDIM + t];
  const float gt = out[(size_t)b * KDIM + t];
  const float coef = (mval + sval * zv) - gt;
  __syncthreads();
  const int i = threadIdx.x * 4;
  float4 g = *(float4*)(out + (size_t)b * KDIM + i);
  float4 mt = *(const float4*)(MT + (size_t)t * KDIM + i);
  g.x += (i + 0 >= t) ? coef * mt.x : 0.f;
  g.y += (i + 1 >= t) ? coef * mt.y : 0.f;
  g.z += (i + 2 >= t) ? coef * mt.z : 0.f;
  g.w += (i + 3 >= t) ? coef * mt.w : 0.f;
  *(float4*)(out + (size_t)b * KDIM + i) = g;
}

// ---------------------------------------------------------------------------
extern "C" void kernel_launch(void* const* d_in, const int* in_sizes, int n_in,
                              void* d_out, int out_size, void* d_ws,
                              size_t ws_size, hipStream_t stream) {
  const float* z = (const float*)d_in[0];
  const int* tgt = (const int*)d_in[1];
  const int* var = (const int*)d_in[2];
  const float* A = (const float*)d_in[3];
  const float* means = (const float*)d_in[4];
  const float* lsc = (const float*)d_in[5];
  float* out = (float*)d_out;

  float* MT = (float*)d_ws;  // 4 MB fp32 (M^T = column-major M)
  float* scr = (float*)((char*)d_ws + (size_t)KDIM * KDIM * 4);  // 2 MB region
  unsigned short* Mbf = (unsigned short*)scr;  // reused after inversion

  // diag 256-super-blocks (4 WGs): diag + h=64 + h=128 combines, fused
  hipLaunchKernelGGL(inv_base, dim3(4), dim3(256), 0, stream, A, MT);
  // h=256: 2 combines * 4*4 tiles
  hipLaunchKernelGGL(comb_p2, dim3(32), dim3(256), 0, stream, A, MT, scr, 256);
  hipLaunchKernelGGL(comb_q2, dim3(32), dim3(256), 0, stream, MT, scr, 256);
  // h=512: 1 combine * 8*8 tiles
  hipLaunchKernelGGL(comb_p2, dim3(64), dim3(256), 0, stream, A, MT, scr, 512);
  hipLaunchKernelGGL(comb_q2, dim3(64), dim3(256), 0, stream, MT, scr, 512);

  hipLaunchKernelGGL(mt2bf, dim3(NBLK * NBLK), dim3(256), 0, stream, MT, Mbf);
  hipLaunchKernelGGL(gemm_mfma, dim3((BDIM / 128) * (KDIM / 128)), dim3(256), 0,
                     stream, z, Mbf, out);
  hipLaunchKernelGGL(correction_k, dim3(BDIM), dim3(256), 0, stream, z, tgt,
                     var, means, lsc, MT, out);
}

// Round 8
// 296.834 us; speedup vs baseline: 1.0509x; 1.0509x over previous
//
#include <hip/hip_runtime.h>
#include <hip/hip_bf16.h>
#include <cstdint>

#define KDIM 1024
#define BDIM 8192
#define VDIM 2
#define NBLK 16  // KDIM / 64

typedef __attribute__((ext_vector_type(8))) short short8;
typedef __attribute__((ext_vector_type(4))) float f32x4;

__device__ inline unsigned short f2bf(float x) {
  unsigned u = __builtin_bit_cast(unsigned, x);
  u = (u + 0x7FFFu + ((u >> 16) & 1u)) >> 16;
  return (unsigned short)u;
}

// ---------------------------------------------------------------------------
// inv_base: one WG per 256-wide diagonal super-block (4 WGs total).
//   Phase A1: serial inversion of eight 32x32 diag sub-blocks (31 short steps,
//             m[32]+rv[8] regs — no spill, unlike the 64-deep r7 version).
//   Phase A2: combine 32->64 per 64-block: X = T2*A21*T1 as two 32^3 LDS MMs,
//             4 blocks in parallel; writes full 64x64 diag inverse to MT.
//   Phase B : two h=64 combines  (M21 = M22*A21*M11), P held in LDS.
//   Phase C : one h=128 combine, P held in LDS, triangular chunk skip.
// MT[j][i] = M[i][j]. Only the upper (i>=j) block-triangle of MT is written.
// ---------------------------------------------------------------------------
__global__ __launch_bounds__(256) void inv_base(const float* __restrict__ A,
                                                float* __restrict__ MT) {
  __shared__ __align__(16) float sh[25600];  // 100 KB arena

  const int sbase = blockIdx.x * 256;
  const int tid = threadIdx.x;

  // ---------------- Phase A1: eight 32x32 serial inversions ----------------
  {
    float* As32 = sh;           // As32[s][r][36], 8*32*36 = 9216 fl
    float* T32 = sh + 16384;    // T32[s][c][36]  (T32[s][c][r] = T_s[r][c])
    // stage: 8 blocks * 32 rows * 8 float4
#pragma unroll
    for (int p = 0; p < 8; ++p) {
      const int idx = p * 256 + tid;
      const int s = idx >> 8, r = (idx >> 3) & 31, c4 = idx & 7;
      const int ob = sbase + 32 * s;
      float4 v = *(const float4*)(A + (size_t)(ob + r) * KDIM + ob + 4 * c4);
      *(float4*)(As32 + s * 1152 + r * 36 + 4 * c4) = v;
    }
    __syncthreads();

    const int s = tid >> 5, c = tid & 31;
    const float* Ab = As32 + s * 1152;
    float m[32];
#pragma unroll
    for (int r = 0; r < 32; ++r) m[r] = (r == c) ? 1.f : 0.f;
    // m[i]==0 for i>=r on threads where it matters (c<r), so full-prefix
    // chunks need no masking; threads with c>=r discard v.
#pragma unroll
    for (int r = 1; r < 32; ++r) {
      const float* Arow = Ab + r * 36;
      const int nch = (r >> 2) + 1;
      float4 rv[8];
#pragma unroll
      for (int ii = 0; ii < 8; ++ii) {
        if (ii >= nch) break;
        rv[ii] = *(const float4*)(Arow + 4 * ii);
      }
      float a0 = 0.f, a1 = 0.f, a2 = 0.f, a3 = 0.f;
#pragma unroll
      for (int ii = 0; ii < 8; ++ii) {
        if (ii >= nch) break;
        a0 += rv[ii].x * m[4 * ii + 0];
        a1 += rv[ii].y * m[4 * ii + 1];
        a2 += rv[ii].z * m[4 * ii + 2];
        a3 += rv[ii].w * m[4 * ii + 3];
      }
      const float v = (a0 + a1) + (a2 + a3);
      m[r] = (r > c) ? v : m[r];
    }
    // T32[s][c][r] = m[r]  (column c contiguous)
#pragma unroll
    for (int r4 = 0; r4 < 8; ++r4) {
      float4 v = make_float4(m[4 * r4], m[4 * r4 + 1], m[4 * r4 + 2], m[4 * r4 + 3]);
      *(float4*)(T32 + s * 1152 + c * 36 + 4 * r4) = v;
    }
  }
  __syncthreads();

  // ---------------- Phase A2: combine 32->64 for 4 blocks in parallel ------
  {
    float* T32 = sh + 16384;
    float* Ls32 = sh;            // Ls32[g][k][36]  (T1 row-major, k-major)
    float* Rs32 = sh + 4608;     // Rs32[g][k][36]  (A21^T: [k][r])
    float* Prm = sh + 9216;      // Prm[g][r][36]   (P row-major)
    float* Xbuf = sh;            // Xbuf[g][j][36]  (Xt) — overlays Ls32 (dead)

    const int g = tid >> 6, tt = tid & 63;
    const int gb = sbase + 64 * g;
    const int tm = tt >> 3, tn = tt & 7;

    // stage Ls32[g][k][j] = T1[k][j] = T32[2g][j][k]
#pragma unroll
    for (int p = 0; p < 16; ++p) {
      const int idx = p * 64 + tt;
      const int k = idx >> 5, j = idx & 31;
      Ls32[g * 1152 + k * 36 + j] = T32[(2 * g) * 1152 + j * 36 + k];
    }
    // stage Rs32[g][k][r] = A21[r][k] = A[(gb+32+r)][gb+k]
#pragma unroll
    for (int p = 0; p < 4; ++p) {
      const int idx = p * 64 + tt;
      const int r = idx >> 3, k4 = idx & 7;
      float4 v = *(const float4*)(A + (size_t)(gb + 32 + r) * KDIM + gb + 4 * k4);
      Rs32[g * 1152 + (4 * k4 + 0) * 36 + r] = v.x;
      Rs32[g * 1152 + (4 * k4 + 1) * 36 + r] = v.y;
      Rs32[g * 1152 + (4 * k4 + 2) * 36 + r] = v.z;
      Rs32[g * 1152 + (4 * k4 + 3) * 36 + r] = v.w;
    }
    __syncthreads();

    // P-MM: Pt[j][r] = sum_k T1[k][j]... (Pt = (A21*T1)^T): per k read
    // Ls32[k][4tm..] (j) and Rs32[k][4tn..] (r)
    float acc[4][4];
#pragma unroll
    for (int a = 0; a < 4; ++a)
#pragma unroll
      for (int b = 0; b < 4; ++b) acc[a][b] = 0.f;
#pragma unroll 4
    for (int k = 0; k < 32; ++k) {
      float4 lv = *(const float4*)&Ls32[g * 1152 + k * 36 + 4 * tm];
      float4 rv = *(const float4*)&Rs32[g * 1152 + k * 36 + 4 * tn];
      const float aa[4] = {lv.x, lv.y, lv.z, lv.w};
      const float bb[4] = {rv.x, rv.y, rv.z, rv.w};
#pragma unroll
      for (int a = 0; a < 4; ++a)
#pragma unroll
        for (int b = 0; b < 4; ++b) acc[a][b] += aa[a] * bb[b];
    }
    // store P row-major: Prm[g][r][j] = Pt[j][r]
#pragma unroll
    for (int a = 0; a < 4; ++a)
#pragma unroll
      for (int b = 0; b < 4; ++b)
        Prm[g * 1152 + (4 * tn + b) * 36 + 4 * tm + a] = acc[a][b];
    __syncthreads();

    // Q-MM: Xt[j][i] = sum_r Pt[j][r] * T2[i][r]; T2[i][r] = T32[2g+1][r][i]
#pragma unroll
    for (int a = 0; a < 4; ++a)
#pragma unroll
      for (int b = 0; b < 4; ++b) acc[a][b] = 0.f;
#pragma unroll 4
    for (int r = 0; r < 32; ++r) {
      float4 lv = *(const float4*)&Prm[g * 1152 + r * 36 + 4 * tm];
      float4 rv = *(const float4*)&T32[(2 * g + 1) * 1152 + r * 36 + 4 * tn];
      const float aa[4] = {lv.x, lv.y, lv.z, lv.w};
      const float bb[4] = {rv.x, rv.y, rv.z, rv.w};
#pragma unroll
      for (int a = 0; a < 4; ++a)
#pragma unroll
        for (int b = 0; b < 4; ++b) acc[a][b] += aa[a] * bb[b];
    }
    // Xbuf[g][j][i] = Xt[j][i]  (Ls32 region is dead; no alias with Prm/T32)
#pragma unroll
    for (int a = 0; a < 4; ++a)
#pragma unroll
      for (int b = 0; b < 4; ++b)
        Xbuf[g * 1152 + (4 * tm + a) * 36 + 4 * tn + b] = acc[a][b];
    __syncthreads();

    // write MT diag block g: thread tt = column c of T_g (64x64)
    const int c = tt;
    if (c < 32) {
#pragma unroll
      for (int r4 = 0; r4 < 8; ++r4)
        *(float4*)(MT + (size_t)(gb + c) * KDIM + gb + 4 * r4) =
            *(const float4*)&T32[(2 * g) * 1152 + c * 36 + 4 * r4];
#pragma unroll
      for (int r4 = 0; r4 < 8; ++r4)
        *(float4*)(MT + (size_t)(gb + c) * KDIM + gb + 32 + 4 * r4) =
            *(const float4*)&Xbuf[g * 1152 + c * 36 + 4 * r4];
    } else {
      const int c2 = c - 32;
      const float4 z4 = make_float4(0.f, 0.f, 0.f, 0.f);
#pragma unroll
      for (int r4 = 0; r4 < 8; ++r4)
        *(float4*)(MT + (size_t)(gb + c) * KDIM + gb + 4 * r4) = z4;
#pragma unroll
      for (int r4 = 0; r4 < 8; ++r4)
        *(float4*)(MT + (size_t)(gb + c) * KDIM + gb + 32 + 4 * r4) =
            *(const float4*)&T32[(2 * g + 1) * 1152 + c2 * 36 + 4 * r4];
    }
  }
  __threadfence();
  __syncthreads();

  // ---------------- Phases B & C: arena-aliased LDS views ----------------
  float(*Ps)[132] = (float(*)[132])sh;            // 128*132 = 16896 fl
  float(*Ls)[68] = (float(*)[68])(sh + 16896);    // 4352 fl
  float(*Rs)[68] = (float(*)[68])(sh + 21248);    // 4352 fl -> 25600 total

  const int k4 = tid & 15, rw = tid >> 4;
  const int tm = tid >> 4, tn = tid & 15;

  // ---------------- Phase B: two h=64 combines ----------------
  for (int cmb = 0; cmb < 2; ++cmb) {
    const int cb = sbase + 128 * cmb;
    __syncthreads();
    // P: Pt[j][r] = sum_c MT11[j][c] * A21[r][c]
#pragma unroll
    for (int p = 0; p < 4; ++p) {
      const int m = p * 16 + rw;
      float4 lv = *(const float4*)(MT + (size_t)(cb + m) * KDIM + cb + 4 * k4);
      Ls[4 * k4 + 0][m] = lv.x;
      Ls[4 * k4 + 1][m] = lv.y;
      Ls[4 * k4 + 2][m] = lv.z;
      Ls[4 * k4 + 3][m] = lv.w;
      float4 rv =
          *(const float4*)(A + (size_t)(cb + 64 + m) * KDIM + cb + 4 * k4);
      Rs[4 * k4 + 0][m] = rv.x;
      Rs[4 * k4 + 1][m] = rv.y;
      Rs[4 * k4 + 2][m] = rv.z;
      Rs[4 * k4 + 3][m] = rv.w;
    }
    __syncthreads();
    float acc[4][4];
#pragma unroll
    for (int a = 0; a < 4; ++a)
#pragma unroll
      for (int b = 0; b < 4; ++b) acc[a][b] = 0.f;
#pragma unroll 4
    for (int k = 0; k < 64; ++k) {
      float4 av = *(const float4*)&Ls[k][4 * tm];
      float4 bv = *(const float4*)&Rs[k][4 * tn];
      const float aa[4] = {av.x, av.y, av.z, av.w};
      const float bb4[4] = {bv.x, bv.y, bv.z, bv.w};
#pragma unroll
      for (int a = 0; a < 4; ++a)
#pragma unroll
        for (int b = 0; b < 4; ++b) acc[a][b] += aa[a] * bb4[b];
    }
    // store P transposed: Ps[r][j] = Pt[j][r]
#pragma unroll
    for (int a = 0; a < 4; ++a)
#pragma unroll
      for (int b = 0; b < 4; ++b) Ps[4 * tn + b][4 * tm + a] = acc[a][b];
    __syncthreads();
    // Q: out[j][r] = sum_c Pt[j][c] * MT22[c][r]
#pragma unroll
    for (int p = 0; p < 4; ++p) {
      const int kk = p * 16 + rw;
      *(float4*)&Rs[kk][4 * k4] =
          *(const float4*)(MT + (size_t)(cb + 64 + kk) * KDIM + cb + 64 + 4 * k4);
    }
    __syncthreads();
#pragma unroll
    for (int a = 0; a < 4; ++a)
#pragma unroll
      for (int b = 0; b < 4; ++b) acc[a][b] = 0.f;
#pragma unroll 4
    for (int k = 0; k < 64; ++k) {
      float4 av = *(const float4*)&Ps[k][4 * tm];
      float4 bv = *(const float4*)&Rs[k][4 * tn];
      const float aa[4] = {av.x, av.y, av.z, av.w};
      const float bb4[4] = {bv.x, bv.y, bv.z, bv.w};
#pragma unroll
      for (int a = 0; a < 4; ++a)
#pragma unroll
        for (int b = 0; b < 4; ++b) acc[a][b] += aa[a] * bb4[b];
    }
#pragma unroll
    for (int a = 0; a < 4; ++a) {
      float4 o = make_float4(acc[a][0], acc[a][1], acc[a][2], acc[a][3]);
      *(float4*)(MT + (size_t)(cb + 4 * tm + a) * KDIM + cb + 64 + 4 * tn) = o;
    }
  }
  __threadfence();
  __syncthreads();

  // ---------------- Phase C: h=128 combine ----------------
  for (int tile = 0; tile < 4; ++tile) {
    const int jt = tile >> 1, rt = tile & 1;
    float acc[4][4];
#pragma unroll
    for (int a = 0; a < 4; ++a)
#pragma unroll
      for (int b = 0; b < 4; ++b) acc[a][b] = 0.f;
    for (int kc = jt; kc < 2; ++kc) {
      __syncthreads();
#pragma unroll
      for (int p = 0; p < 4; ++p) {
        const int m = p * 16 + rw;
        float4 lv = *(const float4*)(MT + (size_t)(sbase + jt * 64 + m) * KDIM +
                                     sbase + kc * 64 + 4 * k4);
        Ls[4 * k4 + 0][m] = lv.x;
        Ls[4 * k4 + 1][m] = lv.y;
        Ls[4 * k4 + 2][m] = lv.z;
        Ls[4 * k4 + 3][m] = lv.w;
        float4 rv =
            *(const float4*)(A + (size_t)(sbase + 128 + rt * 64 + m) * KDIM +
                             sbase + kc * 64 + 4 * k4);
        Rs[4 * k4 + 0][m] = rv.x;
        Rs[4 * k4 + 1][m] = rv.y;
        Rs[4 * k4 + 2][m] = rv.z;
        Rs[4 * k4 + 3][m] = rv.w;
      }
      __syncthreads();
#pragma unroll 4
      for (int k = 0; k < 64; ++k) {
        float4 av = *(const float4*)&Ls[k][4 * tm];
        float4 bv = *(const float4*)&Rs[k][4 * tn];
        const float aa[4] = {av.x, av.y, av.z, av.w};
        const float bb4[4] = {bv.x, bv.y, bv.z, bv.w};
#pragma unroll
        for (int a = 0; a < 4; ++a)
#pragma unroll
          for (int b = 0; b < 4; ++b) acc[a][b] += aa[a] * bb4[b];
      }
    }
    __syncthreads();
#pragma unroll
    for (int a = 0; a < 4; ++a)
#pragma unroll
      for (int b = 0; b < 4; ++b)
        Ps[rt * 64 + 4 * tn + b][jt * 64 + 4 * tm + a] = acc[a][b];
  }
  // Q2: out[j][r] = sum_c P2[j][c]*MT22[c][r]; skip kc>rt (zero)
  for (int tile = 0; tile < 4; ++tile) {
    const int jt = tile >> 1, rt = tile & 1;
    float acc[4][4];
#pragma unroll
    for (int a = 0; a < 4; ++a)
#pragma unroll
      for (int b = 0; b < 4; ++b) acc[a][b] = 0.f;
    for (int kc = 0; kc <= rt; ++kc) {
      __syncthreads();
#pragma unroll
      for (int p = 0; p < 4; ++p) {
        const int kk = p * 16 + rw;
        *(float4*)&Rs[kk][4 * k4] =
            *(const float4*)(MT + (size_t)(sbase + 128 + kc * 64 + kk) * KDIM +
                             sbase + 128 + rt * 64 + 4 * k4);
      }
      __syncthreads();
#pragma unroll 4
      for (int k = 0; k < 64; ++k) {
        float4 av = *(const float4*)&Ps[kc * 64 + k][jt * 64 + 4 * tm];
        float4 bv = *(const float4*)&Rs[k][4 * tn];
        const float aa[4] = {av.x, av.y, av.z, av.w};
        const float bb4[4] = {bv.x, bv.y, bv.z, bv.w};
#pragma unroll
        for (int a = 0; a < 4; ++a)
#pragma unroll
          for (int b = 0; b < 4; ++b) acc[a][b] += aa[a] * bb4[b];
      }
    }
#pragma unroll
    for (int a = 0; a < 4; ++a) {
      float4 o = make_float4(acc[a][0], acc[a][1], acc[a][2], acc[a][3]);
      *(float4*)(MT + (size_t)(sbase + jt * 64 + 4 * tm + a) * KDIM + sbase +
                 128 + rt * 64 + 4 * tn) = o;
    }
  }
}

// ---------------------------------------------------------------------------
// comb_p2: Pt[j][r] = sum_c MT11[j][c] * A21[r][c]   (full-K per tile,
// triangular skip kc>=jt, plain stores — no atomics, no pre-zero).
// grid = combines * t * t,  t = h/64.
// ---------------------------------------------------------------------------
__global__ __launch_bounds__(256) void comb_p2(const float* __restrict__ A,
                                               const float* __restrict__ MT,
                                               float* __restrict__ Pt, int h) {
  const int t = h >> 6;
  int b = blockIdx.x;
  const int rt = b % t; b /= t;
  const int jt = b % t; b /= t;
  const int c = b;
  const int base = c * 2 * h;

  __shared__ float Ls[64][68];
  __shared__ float Rs[64][68];
  const int tid = threadIdx.x;
  const int k4 = tid & 15, rw = tid >> 4;
  const int tm = tid >> 4, tn = tid & 15;

  float acc[4][4];
#pragma unroll
  for (int a = 0; a < 4; ++a)
#pragma unroll
    for (int bb = 0; bb < 4; ++bb) acc[a][bb] = 0.f;

  for (int kc = jt; kc < t; ++kc) {
    __syncthreads();
#pragma unroll
    for (int p = 0; p < 4; ++p) {
      const int m = p * 16 + rw;
      float4 lv = *(const float4*)(MT + (size_t)(base + jt * 64 + m) * KDIM +
                                   base + kc * 64 + 4 * k4);
      Ls[4 * k4 + 0][m] = lv.x;
      Ls[4 * k4 + 1][m] = lv.y;
      Ls[4 * k4 + 2][m] = lv.z;
      Ls[4 * k4 + 3][m] = lv.w;
      float4 rv = *(const float4*)(A + (size_t)(base + h + rt * 64 + m) * KDIM +
                                   base + kc * 64 + 4 * k4);
      Rs[4 * k4 + 0][m] = rv.x;
      Rs[4 * k4 + 1][m] = rv.y;
      Rs[4 * k4 + 2][m] = rv.z;
      Rs[4 * k4 + 3][m] = rv.w;
    }
    __syncthreads();
#pragma unroll 4
    for (int k = 0; k < 64; ++k) {
      float4 av = *(const float4*)&Ls[k][4 * tm];
      float4 bv = *(const float4*)&Rs[k][4 * tn];
      const float aa[4] = {av.x, av.y, av.z, av.w};
      const float bb4[4] = {bv.x, bv.y, bv.z, bv.w};
#pragma unroll
      for (int a = 0; a < 4; ++a)
#pragma unroll
        for (int bb = 0; bb < 4; ++bb) acc[a][bb] += aa[a] * bb4[bb];
    }
  }
#pragma unroll
  for (int a = 0; a < 4; ++a) {
    float4 o = make_float4(acc[a][0], acc[a][1], acc[a][2], acc[a][3]);
    *(float4*)(Pt + (size_t)c * h * h + (size_t)(jt * 64 + 4 * tm + a) * h +
               rt * 64 + 4 * tn) = o;
  }
}

// ---------------------------------------------------------------------------
// comb_q2: MT21t[j][r] = sum_c Pt[j][c] * MT22[c][r]   (skip kc>rt).
// ---------------------------------------------------------------------------
__global__ __launch_bounds__(256) void comb_q2(float* __restrict__ MT,
                                               const float* __restrict__ Pt,
                                               int h) {
  const int t = h >> 6;
  int b = blockIdx.x;
  const int rt = b % t; b /= t;
  const int jt = b % t; b /= t;
  const int c = b;
  const int base = c * 2 * h;
  const float* P0 = Pt + (size_t)c * h * h;

  __shared__ float Ls[64][68];
  __shared__ float Rs[64][68];
  const int tid = threadIdx.x;
  const int k4 = tid & 15, rw = tid >> 4;
  const int tm = tid >> 4, tn = tid & 15;

  float acc[4][4];
#pragma unroll
  for (int a = 0; a < 4; ++a)
#pragma unroll
    for (int bb = 0; bb < 4; ++bb) acc[a][bb] = 0.f;

  for (int kc = 0; kc <= rt; ++kc) {
    __syncthreads();
#pragma unroll
    for (int p = 0; p < 4; ++p) {
      const int m = p * 16 + rw;
      float4 lv = *(const float4*)(P0 + (size_t)(jt * 64 + m) * h + kc * 64 + 4 * k4);
      Ls[4 * k4 + 0][m] = lv.x;
      Ls[4 * k4 + 1][m] = lv.y;
      Ls[4 * k4 + 2][m] = lv.z;
      Ls[4 * k4 + 3][m] = lv.w;
      const int kk = p * 16 + rw;
      *(float4*)&Rs[kk][4 * k4] =
          *(const float4*)(MT + (size_t)(base + h + kc * 64 + kk) * KDIM +
                           base + h + rt * 64 + 4 * k4);
    }
    __syncthreads();
#pragma unroll 4
    for (int k = 0; k < 64; ++k) {
      float4 av = *(const float4*)&Ls[k][4 * tm];
      float4 bv = *(const float4*)&Rs[k][4 * tn];
      const float aa[4] = {av.x, av.y, av.z, av.w};
      const float bb4[4] = {bv.x, bv.y, bv.z, bv.w};
#pragma unroll
      for (int a = 0; a < 4; ++a)
#pragma unroll
        for (int bb = 0; bb < 4; ++bb) acc[a][bb] += aa[a] * bb4[bb];
    }
  }
#pragma unroll
  for (int a = 0; a < 4; ++a) {
    float4 o = make_float4(acc[a][0], acc[a][1], acc[a][2], acc[a][3]);
    *(float4*)(MT + (size_t)(base + jt * 64 + 4 * tm + a) * KDIM + base + h +
               rt * 64 + 4 * tn) = o;
  }
}

// ---------------------------------------------------------------------------
// mt2bf: Mbf[i][k] = bf16(MT[k][i]); tiles with ib<jb are structurally zero
// (MT there is unwritten garbage) — write zeros without reading.
// ---------------------------------------------------------------------------
__global__ __launch_bounds__(256) void mt2bf(const float* __restrict__ MT,
                                             unsigned short* __restrict__ Mbf) {
  const int ib = blockIdx.x & 15;
  const int jb = blockIdx.x >> 4;
  const int i0 = ib * 64, j0 = jb * 64;
  const int tr = threadIdx.x >> 4;
  const int tc = threadIdx.x & 15;

  if (ib < jb) {
    const ushort4 z = {0, 0, 0, 0};
#pragma unroll
    for (int p = 0; p < 4; ++p)
      *(ushort4*)(Mbf + (size_t)(i0 + p * 16 + tr) * KDIM + j0 + 4 * tc) = z;
    return;
  }

  __shared__ float tile[64][65];
#pragma unroll
  for (int p = 0; p < 4; ++p) {
    const int rj = p * 16 + tr;
    float4 v = *(const float4*)(MT + (size_t)(j0 + rj) * KDIM + i0 + 4 * tc);
    tile[rj][4 * tc + 0] = v.x;
    tile[rj][4 * tc + 1] = v.y;
    tile[rj][4 * tc + 2] = v.z;
    tile[rj][4 * tc + 3] = v.w;
  }
  __syncthreads();
#pragma unroll
  for (int p = 0; p < 4; ++p) {
    const int il = p * 16 + tr;
    ushort4 o;
    o.x = f2bf(tile[4 * tc + 0][il]);
    o.y = f2bf(tile[4 * tc + 1][il]);
    o.z = f2bf(tile[4 * tc + 2][il]);
    o.w = f2bf(tile[4 * tc + 3][il]);
    *(ushort4*)(Mbf + (size_t)(i0 + il) * KDIM + j0 + 4 * tc) = o;
  }
}

// ---------------------------------------------------------------------------
// bf16 MFMA GEMM, double-buffered K-loop (one barrier per k-block).
// C[b][i] = sum_k Z[b][k] * Mbf[i][k]   (NT), 128x128 tile, 4 waves.
// ---------------------------------------------------------------------------
#define LDB 72

__global__ __launch_bounds__(256) void gemm_mfma(
    const float* __restrict__ Z, const unsigned short* __restrict__ Mbf,
    float* __restrict__ C) {
  __shared__ unsigned short As[2][128][LDB];
  __shared__ unsigned short Bs[2][128][LDB];

  const int wg = blockIdx.x;
  const int t7 = wg & 7;
  const int ni = (t7 & 1) ? (7 - (t7 >> 1)) : (t7 >> 1);
  const int xb = wg >> 3;
  const int b0 = xb * 128;
  const int i0 = ni * 128;

  const int tid = threadIdx.x;
  const int w = tid >> 6;
  const int lane = tid & 63;
  const int wr = w >> 1, wc = w & 1;
  const int mlane = lane & 15;
  const int q = lane >> 4;

  const int rq = tid >> 4, kq = tid & 15;
  const int cb = tid >> 3, ck = tid & 7;

  f32x4 acc[4][4];
#pragma unroll
  for (int a = 0; a < 4; ++a)
#pragma unroll
    for (int b = 0; b < 4; ++b) acc[a][b] = (f32x4){0.f, 0.f, 0.f, 0.f};

  const int nkb = 2 * (ni + 1);

  float4 zr[8];
  uint4 br[4];

#pragma unroll
  for (int p = 0; p < 8; ++p)
    zr[p] = *(const float4*)(Z + (size_t)(b0 + p * 16 + rq) * KDIM + 4 * kq);
#pragma unroll
  for (int p = 0; p < 4; ++p)
    br[p] = *(const uint4*)(Mbf + (size_t)(i0 + p * 32 + cb) * KDIM + 8 * ck);
#pragma unroll
  for (int p = 0; p < 8; ++p) {
    ushort4 o;
    o.x = f2bf(zr[p].x);
    o.y = f2bf(zr[p].y);
    o.z = f2bf(zr[p].z);
    o.w = f2bf(zr[p].w);
    *(ushort4*)&As[0][p * 16 + rq][4 * kq] = o;
  }
#pragma unroll
  for (int p = 0; p < 4; ++p) *(uint4*)&Bs[0][p * 32 + cb][8 * ck] = br[p];
  __syncthreads();

  for (int kb = 0; kb < nkb; ++kb) {
    const int cur = kb & 1;
    const bool more = (kb + 1 < nkb);
    if (more) {
      const int k0 = (kb + 1) * 64;
#pragma unroll
      for (int p = 0; p < 8; ++p)
        zr[p] = *(const float4*)(Z + (size_t)(b0 + p * 16 + rq) * KDIM + k0 +
                                 4 * kq);
#pragma unroll
      for (int p = 0; p < 4; ++p)
        br[p] = *(const uint4*)(Mbf + (size_t)(i0 + p * 32 + cb) * KDIM + k0 +
                                8 * ck);
    }
#pragma unroll
    for (int ks = 0; ks < 2; ++ks) {
      const int kf = ks * 32 + q * 8;
      short8 av[4], bv[4];
#pragma unroll
      for (int a = 0; a < 4; ++a)
        av[a] = *(const short8*)&As[cur][wr * 64 + 16 * a + mlane][kf];
#pragma unroll
      for (int b = 0; b < 4; ++b)
        bv[b] = *(const short8*)&Bs[cur][wc * 64 + 16 * b + mlane][kf];
#pragma unroll
      for (int a = 0; a < 4; ++a)
#pragma unroll
        for (int b = 0; b < 4; ++b)
          acc[a][b] = __builtin_amdgcn_mfma_f32_16x16x32_bf16(av[a], bv[b],
                                                              acc[a][b], 0, 0, 0);
    }
    if (more) {
#pragma unroll
      for (int p = 0; p < 8; ++p) {
        ushort4 o;
        o.x = f2bf(zr[p].x);
        o.y = f2bf(zr[p].y);
        o.z = f2bf(zr[p].z);
        o.w = f2bf(zr[p].w);
        *(ushort4*)&As[cur ^ 1][p * 16 + rq][4 * kq] = o;
      }
#pragma unroll
      for (int p = 0; p < 4; ++p)
        *(uint4*)&Bs[cur ^ 1][p * 32 + cb][8 * ck] = br[p];
    }
    __syncthreads();
  }

#pragma unroll
  for (int a = 0; a < 4; ++a) {
    const int row0 = b0 + wr * 64 + 16 * a + q * 4;
#pragma unroll
    for (int b = 0; b < 4; ++b) {
      const int col = i0 + wc * 64 + 16 * b + mlane;
      float* Cp = C + (size_t)row0 * KDIM + col;
      Cp[0 * KDIM] = acc[a][b][0];
      Cp[1 * KDIM] = acc[a][b][1];
      Cp[2 * KDIM] = acc[a][b][2];
      Cp[3 * KDIM] = acc[a][b][3];
    }
  }
}

// ---------------------------------------------------------------------------
// correction_k: u[b,:] = g[b,:] + (v - g[b,t]) * MT[t,:], masked to i >= t
// (MT[t][i] for i below t's diagonal block is unwritten garbage; true M
// column t is zero there anyway).
// ---------------------------------------------------------------------------
__global__ __launch_bounds__(256) void correction_k(
    const float* __restrict__ z, const int* __restrict__ tgt,
    const int* __restrict__ var, const float* __restrict__ means,
    const float* __restrict__ lsc, const float* __restrict__ MT,
    float* __restrict__ out) {
  const int b = blockIdx.x;
  const int t = tgt[b];
  if (t < 0) return;
  const int v = var[b];
  const float mval = means[t * VDIM + v];
  const float sval = expf(lsc[t * VDIM + v]);
  const float zv = z[(size_t)b * KDIM + t];
  const float gt = out[(size_t)b * KDIM + t];
  const float coef = (mval + sval * zv) - gt;
  __syncthreads();
  const int i = threadIdx.x * 4;
  float4 g = *(float4*)(out + (size_t)b * KDIM + i);
  float4 mt = *(const float4*)(MT + (size_t)t * KDIM + i);
  g.x += (i + 0 >= t) ? coef * mt.x : 0.f;
  g.y += (i + 1 >= t) ? coef * mt.y : 0.f;
  g.z += (i + 2 >= t) ? coef * mt.z : 0.f;
  g.w += (i + 3 >= t) ? coef * mt.w : 0.f;
  *(float4*)(out + (size_t)b * KDIM + i) = g;
}

// ---------------------------------------------------------------------------
extern "C" void kernel_launch(void* const* d_in, const int* in_sizes, int n_in,
                              void* d_out, int out_size, void* d_ws,
                              size_t ws_size, hipStream_t stream) {
  const float* z = (const float*)d_in[0];
  const int* tgt = (const int*)d_in[1];
  const int* var = (const int*)d_in[2];
  const float* A = (const float*)d_in[3];
  const float* means = (const float*)d_in[4];
  const float* lsc = (const float*)d_in[5];
  float* out = (float*)d_out;

  float* MT = (float*)d_ws;  // 4 MB fp32 (M^T = column-major M)
  float* scr = (float*)((char*)d_ws + (size_t)KDIM * KDIM * 4);  // 2 MB region
  unsigned short* Mbf = (unsigned short*)scr;  // reused after inversion

  // diag 256-super-blocks (4 WGs): 32-diag + 32->64 + h=64 + h=128, fused
  hipLaunchKernelGGL(inv_base, dim3(4), dim3(256), 0, stream, A, MT);
  // h=256: 2 combines * 4*4 tiles
  hipLaunchKernelGGL(comb_p2, dim3(32), dim3(256), 0, stream, A, MT, scr, 256);
  hipLaunchKernelGGL(comb_q2, dim3(32), dim3(256), 0, stream, MT, scr, 256);
  // h=512: 1 combine * 8*8 tiles
  hipLaunchKernelGGL(comb_p2, dim3(64), dim3(256), 0, stream, A, MT, scr, 512);
  hipLaunchKernelGGL(comb_q2, dim3(64), dim3(256), 0, stream, MT, scr, 512);

  hipLaunchKernelGGL(mt2bf, dim3(NBLK * NBLK), dim3(256), 0, stream, MT, Mbf);
  hipLaunchKernelGGL(gemm_mfma, dim3((BDIM / 128) * (KDIM / 128)), dim3(256), 0,
                     stream, z, Mbf, out);
  hipLaunchKernelGGL(correction_k, dim3(BDIM), dim3(256), 0, stream, z, tgt,
                     var, means, lsc, MT, out);
}